// Round 14
// baseline (380.400 us; speedup 1.0000x reference)
//
#include <hip/hip_runtime.h>
#include <hip/hip_cooperative_groups.h>
#include <math.h>

namespace cg = cooperative_groups;

namespace {
constexpr int Mz = 256, Lz = 24, Sz = 22, Bz = 4;
constexpr int Wz = Mz + Lz - 1;        // 279
constexpr int ST = 26;                  // Ys float2 stride (b64 conflict-free)
constexpr int NBLK = Bz * Mz;           // 1024
constexpr int NPASS = 7;                // ceil(279 / 41) systolic passes
constexpr double SIGM_DEN = (double)Mz * (double)Wz * (double)Bz * 1e4;
}

__device__ __forceinline__ unsigned int enc_f32(float f) {
  unsigned int u = __float_as_uint(f);
  return (u & 0x80000000u) ? ~u : (u | 0x80000000u);
}
__device__ __forceinline__ float dec_f32(unsigned int e) {
  unsigned int u = (e & 0x80000000u) ? (e ^ 0x80000000u) : ~e;
  return __uint_as_float(u);
}

// lane j <- lane j+1 (srcLane = laneId+1 = DPP wave_shl:1 = 0x130); lane 63 <- 0.
__device__ __forceinline__ float rot_down1(float v) {
  return __int_as_float(
      __builtin_amdgcn_update_dpp(0, __float_as_int(v), 0x130, 0xF, 0xF, true));
}

// ---------- shared device helpers (Y-build used by both paths) ----------
template <typename YSTORE>
__device__ __forceinline__ double y_build(const float* __restrict__ xp,
                                          const float* __restrict__ Hp,
                                          int j, int wv, YSTORE&& store)
{
  double local = 0.0;
  for (int pp = 0; pp < 2; ++pp) {
    const int p = wv + 4 * pp;
    if (p >= NPASS) break;                 // wave-uniform
    const int W0 = 41 * p;
    const int n = W0 - 23 + j;             // lane-owned input row
    const bool valid = (n >= 0) && (n < Mz);

    float hr[Sz], xr[Lz];
    if (valid) {
      const float2* __restrict__ h2 = (const float2*)(Hp + n * Sz);
      #pragma unroll
      for (int k = 0; k < 11; ++k) { const float2 h = h2[k]; hr[2*k] = h.x; hr[2*k+1] = h.y; }
      const float4* __restrict__ x4 = (const float4*)(xp + n * Lz);
      #pragma unroll
      for (int k = 0; k < 6; ++k) {
        const float4 t = x4[k];
        xr[4*k] = t.x; xr[4*k+1] = t.y; xr[4*k+2] = t.z; xr[4*k+3] = t.w;
      }
    } else {
      #pragma unroll
      for (int k = 0; k < Sz; ++k) hr[k] = 0.f;
      #pragma unroll
      for (int k = 0; k < Lz; ++k) xr[k] = 0.f;
    }

    float acc[Sz];
    #pragma unroll
    for (int s = 0; s < Sz; ++s) acc[s] = 0.f;

    // invariant: entering step i, lane j's acc = partial Y[n_j + i]
    #pragma unroll
    for (int i = 0; i < Lz; ++i) {
      #pragma unroll
      for (int s = 0; s < Sz; ++s) acc[s] = fmaf(hr[s], xr[i], acc[s]);
      if (i < Lz - 1) {
        #pragma unroll
        for (int s = 0; s < Sz; ++s) acc[s] = rot_down1(acc[s]);
      }
    }

    const int w = W0 + j;                  // lanes 0..40 hold complete Y[W0+j]
    if (j <= 40 && w < Wz) {
      store(w, acc);
      #pragma unroll
      for (int s = 0; s < Sz; ++s) local += (double)acc[s] * acc[s];
    }
  }
  return local;
}

// ---------------- fused cooperative kernel ----------------
__global__ __launch_bounds__(256, 4) void k_fused(const float* __restrict__ x,
                                                  const float* __restrict__ H,
                                                  const float* __restrict__ eps,
                                                  float* __restrict__ out,
                                                  double* __restrict__ sumsq,
                                                  unsigned int* __restrict__ maxenc)
{
  __shared__ __align__(16) float Ys[Wz * ST];   // 29016 B; reused as Xl[256*25]
  __shared__ float eps_s[Wz];
  __shared__ double wred[4];
  __shared__ float wredf[4];

  const int tid = threadIdx.x;
  const int j  = tid & 63;
  const int wv = tid >> 6;
  const int bm = blockIdx.x;
  const int m = bm & 255;
  const float* __restrict__ xp = x + (size_t)bm * (Mz * Lz);
  const float* __restrict__ Hp = H + (size_t)m * (Mz * Sz);

  for (int e = tid; e < Wz; e += 256) eps_s[e] = eps[bm * Wz + e];

  double local = y_build(xp, Hp, j, wv, [&](int w, const float* acc) {
    float2* __restrict__ yrow = (float2*)&Ys[w * ST];
    #pragma unroll
    for (int k = 0; k < 11; ++k) yrow[k] = make_float2(acc[2*k], acc[2*k+1]);
  });

  for (int off = 32; off > 0; off >>= 1) local += __shfl_down(local, off, 64);
  if ((tid & 63) == 0) wred[wv] = local;
  __syncthreads();
  if (tid == 0) atomicAdd(sumsq, wred[0] + wred[1] + wred[2] + wred[3]);

  // ---- X0 phase -> 24 regs; thread owns row n = tid; hsumloc from hr ----
  float X0r[Lz];
  float hsumloc;
  {
    const int n = tid;
    float hr[Sz];
    const float2* __restrict__ h2 = (const float2*)(Hp + n * Sz);
    #pragma unroll
    for (int k = 0; k < 11; ++k) { const float2 h = h2[k]; hr[2*k] = h.x; hr[2*k+1] = h.y; }
    float a = 0.f;
    #pragma unroll
    for (int s = 0; s < Sz; ++s) a += hr[s];
    hsumloc = a;
    #pragma unroll
    for (int l = 0; l < Lz; ++l) {
      const float2* __restrict__ yr = (const float2*)&Ys[(n + l) * ST];
      float a0 = 0.f, a1 = 0.f;
      #pragma unroll
      for (int k = 0; k < 11; ++k) {
        const float2 y = yr[k];
        a0 = fmaf(y.x, hr[2*k],   a0);
        a1 = fmaf(y.y, hr[2*k+1], a1);
      }
      X0r[l] = a0 + a1;
    }
  }

  cg::this_grid().sync();                  // sumsq final everywhere

  const double ss = __hip_atomic_load(sumsq, __ATOMIC_ACQUIRE, __HIP_MEMORY_SCOPE_AGENT);
  const float c = sqrtf((float)(ss / SIGM_DEN));
  const float hv = c * hsumloc;
  float mx = -3.4e38f;
  #pragma unroll
  for (int l = 0; l < Lz; ++l) {
    X0r[l] = fmaf(hv, eps_s[tid + l], X0r[l]);
    mx = fmaxf(mx, X0r[l]);
  }
  for (int off = 32; off > 0; off >>= 1) mx = fmaxf(mx, __shfl_down(mx, off, 64));
  if ((tid & 63) == 0) wredf[wv] = mx;
  __syncthreads();
  if (tid == 0) {
    float bmx = fmaxf(fmaxf(wredf[0], wredf[1]), fmaxf(wredf[2], wredf[3]));
    atomicMax(maxenc, enc_f32(bmx));
  }

  cg::this_grid().sync();                  // max final everywhere

  const unsigned int me = __hip_atomic_load(maxenc, __ATOMIC_ACQUIRE, __HIP_MEMORY_SCOPE_AGENT);
  const float inv = 1.0f / dec_f32(me);
  float* __restrict__ Xl = Ys;             // reuse (all Ys reads done pre-sync)
  #pragma unroll
  for (int l = 0; l < Lz; ++l) Xl[tid * 25 + l] = X0r[l] * inv;
  __syncthreads();
  float4* __restrict__ op4 = (float4*)(out + (size_t)bm * (Mz * Lz));
  #pragma unroll
  for (int q = 0; q < 6; ++q) {
    const int idx4 = q * 256 + tid;
    const int n = idx4 / 6;
    const int l0 = 4 * (idx4 - 6 * n);
    const float* __restrict__ src = &Xl[n * 25 + l0];
    op4[idx4] = make_float4(src[0], src[1], src[2], src[3]);
  }
}

// ---------------- fallback path (measured round-11, 124.3 us) ----------------
__global__ __launch_bounds__(256, 4) void k_fwd(const float* __restrict__ x,
                                                const float* __restrict__ H,
                                                float* __restrict__ X0,
                                                double* __restrict__ sumsq,
                                                float* __restrict__ hsum)
{
  __shared__ __align__(16) float Ys[Wz * ST];
  __shared__ double wred[4];

  const int tid = threadIdx.x;
  const int j  = tid & 63;
  const int wv = tid >> 6;
  const int b = blockIdx.x >> 8;
  const int m = blockIdx.x & 255;
  const float* __restrict__ xp = x + (size_t)(b * Mz + m) * (Mz * Lz);
  const float* __restrict__ Hp = H + (size_t)m * (Mz * Sz);

  double local = y_build(xp, Hp, j, wv, [&](int w, const float* acc) {
    float2* __restrict__ yrow = (float2*)&Ys[w * ST];
    #pragma unroll
    for (int k = 0; k < 11; ++k) yrow[k] = make_float2(acc[2*k], acc[2*k+1]);
  });

  for (int off = 32; off > 0; off >>= 1) local += __shfl_down(local, off, 64);
  if ((tid & 63) == 0) wred[wv] = local;
  __syncthreads();
  if (tid == 0) atomicAdd(sumsq, wred[0] + wred[1] + wred[2] + wred[3]);

  {
    const int n = tid;
    float hr[Sz];
    const float2* __restrict__ h2 = (const float2*)(Hp + n * Sz);
    #pragma unroll
    for (int k = 0; k < 11; ++k) { const float2 h = h2[k]; hr[2*k] = h.x; hr[2*k+1] = h.y; }
    if (b == 0) {
      float a = 0.f;
      #pragma unroll
      for (int s = 0; s < Sz; ++s) a += hr[s];
      hsum[(m << 8) + n] = a;
    }
    float4* __restrict__ Xp4 =
        (float4*)(X0 + (size_t)(b * Mz + m) * (Mz * Lz) + n * Lz);
    #pragma unroll
    for (int q = 0; q < 6; ++q) {
      float o[4];
      #pragma unroll
      for (int jj = 0; jj < 4; ++jj) {
        const int l = 4 * q + jj;
        const float2* __restrict__ yr = (const float2*)&Ys[(n + l) * ST];
        float a0 = 0.f, a1 = 0.f;
        #pragma unroll
        for (int k = 0; k < 11; ++k) {
          const float2 y = yr[k];
          a0 = fmaf(y.x, hr[2*k],   a0);
          a1 = fmaf(y.y, hr[2*k+1], a1);
        }
        o[jj] = a0 + a1;
      }
      Xp4[q] = make_float4(o[0], o[1], o[2], o[3]);
    }
  }
}

__global__ __launch_bounds__(256) void k_max(const float* __restrict__ X0,
                                             const float* __restrict__ eps,
                                             const float* __restrict__ hsum,
                                             const double* __restrict__ sumsq,
                                             unsigned int* __restrict__ maxenc)
{
  const float c = sqrtf((float)(*sumsq / SIGM_DEN));
  const int tid = threadIdx.x;
  const int bm = blockIdx.x;
  const int m = bm & 255;
  const float4* __restrict__ slab = (const float4*)(X0 + (size_t)bm * (Mz * Lz));
  const float* __restrict__ ep = eps + bm * Wz;
  const float* __restrict__ hs = hsum + (m << 8);

  float mx = -3.4e38f;
  #pragma unroll
  for (int q = 0; q < 6; ++q) {
    const int idx4 = q * 256 + tid;
    const int n = idx4 / 6;
    const int l0 = 4 * (idx4 - 6 * n);
    const float4 t = slab[idx4];
    const float hv = c * hs[n];
    const float* __restrict__ e4 = ep + n + l0;
    mx = fmaxf(mx, fmaf(hv, e4[0], t.x));
    mx = fmaxf(mx, fmaf(hv, e4[1], t.y));
    mx = fmaxf(mx, fmaf(hv, e4[2], t.z));
    mx = fmaxf(mx, fmaf(hv, e4[3], t.w));
  }
  for (int off = 32; off > 0; off >>= 1) mx = fmaxf(mx, __shfl_down(mx, off, 64));
  __shared__ float wredf[4];
  const int lane = tid & 63, wid = tid >> 6;
  if (lane == 0) wredf[wid] = mx;
  __syncthreads();
  if (tid == 0) {
    float bmx = fmaxf(fmaxf(wredf[0], wredf[1]), fmaxf(wredf[2], wredf[3]));
    atomicMax(maxenc, enc_f32(bmx));
  }
}

__global__ __launch_bounds__(256) void k_final(float* __restrict__ Xio,
                                               const float* __restrict__ eps,
                                               const float* __restrict__ hsum,
                                               const double* __restrict__ sumsq,
                                               const unsigned int* __restrict__ maxenc)
{
  const float c = sqrtf((float)(*sumsq / SIGM_DEN));
  const float inv = 1.0f / dec_f32(*maxenc);
  const int tid = threadIdx.x;
  const int bm = blockIdx.x;
  const int m = bm & 255;
  float4* __restrict__ slab = (float4*)(Xio + (size_t)bm * (Mz * Lz));
  const float* __restrict__ ep = eps + bm * Wz;
  const float* __restrict__ hs = hsum + (m << 8);

  #pragma unroll
  for (int q = 0; q < 6; ++q) {
    const int idx4 = q * 256 + tid;
    const int n = idx4 / 6;
    const int l0 = 4 * (idx4 - 6 * n);
    float4 t = slab[idx4];
    const float hv = c * hs[n];
    const float* __restrict__ e4 = ep + n + l0;
    t.x = fmaf(hv, e4[0], t.x) * inv;
    t.y = fmaf(hv, e4[1], t.y) * inv;
    t.z = fmaf(hv, e4[2], t.z) * inv;
    t.w = fmaf(hv, e4[3], t.w) * inv;
    slab[idx4] = t;
  }
}

extern "C" void kernel_launch(void* const* d_in, const int* in_sizes, int n_in,
                              void* d_out, int out_size, void* d_ws, size_t ws_size,
                              hipStream_t stream) {
  const float* x   = (const float*)d_in[0];   // (4,256,256,24)
  const float* H   = (const float*)d_in[1];   // (1,256,256,1,22)
  const float* eps = (const float*)d_in[2];   // (4,256,279,1)
  float* out = (float*)d_out;                 // (4,256,256,24)

  double*       sumsq  = (double*)d_ws;
  unsigned int* maxenc = (unsigned int*)((char*)d_ws + 8);
  float*        hsum   = (float*)((char*)d_ws + 16);   // 256KB

  hipMemsetAsync(d_ws, 0, 16, stream);        // zero sumsq + maxenc

  void* args[] = { (void*)&x, (void*)&H, (void*)&eps, (void*)&out,
                   (void*)&sumsq, (void*)&maxenc };
  hipError_t err = hipLaunchCooperativeKernel((void*)k_fused, dim3(NBLK), dim3(256),
                                              args, 0, stream);
  if (err != hipSuccess) {
    // deterministic fallback: measured round-11 3-kernel path
    k_fwd   <<<NBLK, 256, 0, stream>>>(x, H, out, sumsq, hsum);
    k_max   <<<NBLK, 256, 0, stream>>>(out, eps, hsum, sumsq, maxenc);
    k_final <<<NBLK, 256, 0, stream>>>(out, eps, hsum, sumsq, maxenc);
  }
}